// Round 1
// baseline (142325.464 us; speedup 1.0000x reference)
//
#include <hip/hip_runtime.h>
#include <math.h>

// Problem constants (from reference): U=H=1024, B=32, T=256.
#define UU 1024
#define BB 32
#define TT 256
#define KC 64

// ---------------------------------------------------------------------------
// Weight transpose+pack: from row-major W_ih/W_hh (3U x U) into
//   A4[k][j][4] = {ih_r, ih_z, ih_n, hh_r}   (float4-aligned)
//   B2[k][j][2] = {hh_z, hh_n}               (float2-aligned)
// so the fused GRU kernel loads coalesced along j for each k.
// ---------------------------------------------------------------------------
__global__ void transpack_kernel(const float* __restrict__ Wih,
                                 const float* __restrict__ Whh,
                                 float* __restrict__ A4,
                                 float* __restrict__ B2) {
    __shared__ float s[6][32][33];
    int bk = blockIdx.x & 31;   // k tile
    int bj = blockIdx.x >> 5;   // j tile
    int k0 = bk * 32, j0 = bj * 32;
    int tid = threadIdx.x;
    int kc = tid & 31, jr = tid >> 5;
    for (int g = 0; g < 6; ++g) {
        const float* src = (g < 3 ? Wih : Whh) + ((size_t)((g % 3) * UU + j0)) * UU + k0;
        for (int j2 = jr; j2 < 32; j2 += 8)
            s[g][kc][j2] = src[(size_t)j2 * UU + kc];
    }
    __syncthreads();
    // A4 tile: 32k * 32j * 4 = 4096 floats, coalesced writes
    for (int it = 0; it < 16; ++it) {
        int e = it * 256 + tid;
        int kk = e >> 7, rem = e & 127, jj = rem >> 2, c = rem & 3;
        A4[((size_t)(k0 + kk) * UU + j0 + jj) * 4 + c] = s[c][kk][jj];
    }
    // B2 tile: 32k * 32j * 2 = 2048 floats
    for (int it = 0; it < 8; ++it) {
        int e = it * 256 + tid;
        int kk = e >> 6, rem = e & 63, jj = rem >> 1, c = rem & 1;
        B2[((size_t)(k0 + kk) * UU + j0 + jj) * 2 + c] = s[4 + c][kk][jj];
    }
}

// ---------------------------------------------------------------------------
// Precompute q_all[t][b][u] = sum_k inputs[b][t][k] * global_W[k][u]
// Grid: (8192/32 row tiles, 1024/32 col tiles). Block 256 threads:
// thread (rr = tid>>3, ju = tid&7) accumulates 4 consecutive u.
// ---------------------------------------------------------------------------
__global__ void qall_kernel(const float* __restrict__ x,
                            const float* __restrict__ gW,
                            float* __restrict__ q) {
    __shared__ float xs[32][KC + 1];
    int r0 = blockIdx.x * 32, u0 = blockIdx.y * 32;
    int tid = threadIdx.x;
    int rr = tid >> 3, ju = tid & 7;
    float4 acc = {0.f, 0.f, 0.f, 0.f};
    for (int k0 = 0; k0 < UU; k0 += KC) {
        for (int e = tid; e < 32 * KC; e += 256) {
            int lr = e >> 6, lk = e & 63;
            int r = r0 + lr;
            int tt = r >> 5, bb = r & 31;  // q_all row r = t*32 + b
            xs[lr][lk] = x[((size_t)bb * TT + tt) * UU + k0 + lk];
        }
        __syncthreads();
        #pragma unroll 4
        for (int kk = 0; kk < KC; ++kk) {
            float4 gv = *(const float4*)&gW[(size_t)(k0 + kk) * UU + u0 + ju * 4];
            float xv = xs[rr][kk];
            acc.x += xv * gv.x; acc.y += xv * gv.y;
            acc.z += xv * gv.z; acc.w += xv * gv.w;
        }
        __syncthreads();
    }
    *(float4*)&q[(size_t)(r0 + rr) * UU + u0 + ju * 4] = acc;
}

__global__ void init_kernel(float* __restrict__ hist0, float* __restrict__ pbuf) {
    int i = blockIdx.x * 256 + threadIdx.x;  // 32768 = B*U
    hist0[i] = 0.f;
    pbuf[i] = 0.f;
    pbuf[BB * UU + i] = 0.f;
}

// ---------------------------------------------------------------------------
// Fused GRU cell: computes h' = GRU(x, h) for 8 output columns per block,
// all 32 batches. x = xA (stride sxA) [+ xB (stride U)], h = hIn (stride sh,
// nullptr -> zeros). Weights from packed A4/B2. Output to hOut (stride sout).
// ---------------------------------------------------------------------------
__device__ __forceinline__ void gru_cell_body(
    int blk, int tid,
    const float* __restrict__ xA, size_t sxA,
    const float* __restrict__ xB,
    const float* __restrict__ hIn, size_t sh,
    const float* __restrict__ A4, const float* __restrict__ B2,
    const float* __restrict__ bih, const float* __restrict__ bhh,
    float* __restrict__ hOut, size_t sout) {
    __shared__ float xs[BB][KC + 1];
    __shared__ float hs[BB][KC + 1];
    int b = tid >> 3, jj = tid & 7;
    int j = blk * 8 + jj;
    float air = 0.f, aiz = 0.f, ain = 0.f, ahr = 0.f, ahz = 0.f, ahn = 0.f;
    for (int k0 = 0; k0 < UU; k0 += KC) {
        for (int e = tid; e < BB * KC; e += 256) {
            int lb = e >> 6, lk = e & 63;
            float xv = xA[(size_t)lb * sxA + k0 + lk];
            if (xB) xv += xB[(size_t)lb * UU + k0 + lk];
            xs[lb][lk] = xv;
            hs[lb][lk] = hIn ? hIn[(size_t)lb * sh + k0 + lk] : 0.f;
        }
        __syncthreads();
        #pragma unroll 4
        for (int kk = 0; kk < KC; ++kk) {
            const float4 wa = *(const float4*)&A4[((size_t)(k0 + kk) * UU + j) * 4];
            const float2 wb = *(const float2*)&B2[((size_t)(k0 + kk) * UU + j) * 2];
            float xv = xs[b][kk], hv = hs[b][kk];
            air += xv * wa.x; aiz += xv * wa.y; ain += xv * wa.z;
            ahr += hv * wa.w; ahz += hv * wb.x; ahn += hv * wb.y;
        }
        __syncthreads();
    }
    float hprev = hIn ? hIn[(size_t)b * sh + j] : 0.f;
    float r = 1.f / (1.f + expf(-(air + bih[j] + ahr + bhh[j])));
    float z = 1.f / (1.f + expf(-(aiz + bih[UU + j] + ahz + bhh[UU + j])));
    float n = tanhf(ain + bih[2 * UU + j] + r * (ahn + bhh[2 * UU + j]));
    hOut[(size_t)b * sout + j] = (1.f - z) * n + z * hprev;
}

// ---------------------------------------------------------------------------
// Attention for one batch b: scores over hist[0..t], softmax, context vector.
// ---------------------------------------------------------------------------
__device__ __forceinline__ void attention_body(
    int b, int tid, int t,
    const float* __restrict__ hist,
    const float* __restrict__ qrow,  // q_all + t*B*U
    float* __restrict__ ct) {
    __shared__ float sc[TT + 1];
    __shared__ float red[16];
    int nt = t + 1;  // history rows 0..t
    int wave = tid >> 6, lane = tid & 63;
    const float* q = qrow + (size_t)b * UU;
    for (int tp = wave; tp < nt; tp += 4) {
        const float* hr = hist + ((size_t)tp * BB + b) * UU;
        float s = 0.f;
        #pragma unroll
        for (int m = 0; m < 4; ++m) {
            float4 hv = *(const float4*)&hr[m * 256 + lane * 4];
            float4 qv = *(const float4*)&q[m * 256 + lane * 4];
            s += hv.x * qv.x + hv.y * qv.y + hv.z * qv.z + hv.w * qv.w;
        }
        #pragma unroll
        for (int off = 32; off; off >>= 1) s += __shfl_xor(s, off);
        if (lane == 0) sc[tp] = s;
    }
    __syncthreads();
    float v0 = (tid < nt) ? sc[tid] : -INFINITY;
    float v1 = (tid + 256 < nt) ? sc[tid + 256] : -INFINITY;
    float mx = fmaxf(v0, v1);
    #pragma unroll
    for (int off = 32; off; off >>= 1) mx = fmaxf(mx, __shfl_xor(mx, off));
    if (lane == 0) red[wave] = mx;
    __syncthreads();
    mx = fmaxf(fmaxf(red[0], red[1]), fmaxf(red[2], red[3]));
    float e0 = (tid < nt) ? expf(v0 - mx) : 0.f;
    float e1 = (tid + 256 < nt) ? expf(v1 - mx) : 0.f;
    float sum = e0 + e1;
    #pragma unroll
    for (int off = 32; off; off >>= 1) sum += __shfl_xor(sum, off);
    if (lane == 0) red[8 + wave] = sum;
    __syncthreads();
    float inv = 1.f / (red[8] + red[9] + red[10] + red[11]);
    __syncthreads();
    if (tid < nt) sc[tid] = e0 * inv;
    if (tid + 256 < nt) sc[tid + 256] = e1 * inv;
    __syncthreads();
    int u0 = tid * 4;
    float4 acc = {0.f, 0.f, 0.f, 0.f};
    for (int tp = 0; tp < nt; ++tp) {
        float a = sc[tp];
        float4 hv = *(const float4*)&hist[((size_t)tp * BB + b) * UU + u0];
        acc.x += a * hv.x; acc.y += a * hv.y;
        acc.z += a * hv.z; acc.w += a * hv.w;
    }
    *(float4*)&ct[(size_t)b * UU + u0] = acc;
}

// K1: g-cell (blocks 0..127) + attention (blocks 128..159), independent work.
__global__ void k1_kernel(const float* __restrict__ inputs, int t,
                          const float* __restrict__ pbuf_cur,
                          const float* __restrict__ hist_t,
                          float* __restrict__ hist_t1,
                          const float* __restrict__ A4g, const float* __restrict__ B2g,
                          const float* __restrict__ gbih, const float* __restrict__ gbhh,
                          const float* __restrict__ hist,
                          const float* __restrict__ qall,
                          float* __restrict__ ct) {
    if (blockIdx.x < 128) {
        gru_cell_body(blockIdx.x, threadIdx.x,
                      inputs + (size_t)t * UU, (size_t)TT * UU,
                      pbuf_cur,
                      hist_t, UU,
                      A4g, B2g, gbih, gbhh,
                      hist_t1, UU);
    } else {
        attention_body(blockIdx.x - 128, threadIdx.x, t,
                       hist, qall + (size_t)t * BB * UU, ct);
    }
}

// K2: p-cell
__global__ void k2_kernel(const float* __restrict__ inputs, int t,
                          const float* __restrict__ ct,
                          const float* __restrict__ pbuf_cur,
                          const float* __restrict__ A4p, const float* __restrict__ B2p,
                          const float* __restrict__ pbih, const float* __restrict__ pbhh,
                          float* __restrict__ pnew) {
    gru_cell_body(blockIdx.x, threadIdx.x,
                  inputs + (size_t)t * UU, (size_t)TT * UU,
                  ct,
                  pbuf_cur, UU,
                  A4p, B2p, pbih, pbhh,
                  pnew, UU);
}

// K3: e-cell (writes output row t) + copy p_new into the persistent p buffer.
__global__ void k3_kernel(const float* __restrict__ pnew,
                          const float* __restrict__ eprev,  // null at t=0
                          const float* __restrict__ A4e, const float* __restrict__ B2e,
                          const float* __restrict__ ebih, const float* __restrict__ ebhh,
                          float* __restrict__ eout,
                          float* __restrict__ pstore) {
    gru_cell_body(blockIdx.x, threadIdx.x,
                  pnew, UU,
                  nullptr,
                  eprev, (size_t)TT * UU,
                  A4e, B2e, ebih, ebhh,
                  eout, (size_t)TT * UU);
    int gi = blockIdx.x * 256 + threadIdx.x;  // 128*256 = B*U
    pstore[gi] = pnew[gi];
}

extern "C" void kernel_launch(void* const* d_in, const int* in_sizes, int n_in,
                              void* d_out, int out_size, void* d_ws, size_t ws_size,
                              hipStream_t stream) {
    (void)in_sizes; (void)n_in; (void)out_size; (void)ws_size;
    const float* inputs = (const float*)d_in[0];
    const float* gW   = (const float*)d_in[1];
    const float* gWih = (const float*)d_in[2];
    const float* gWhh = (const float*)d_in[3];
    const float* gbih = (const float*)d_in[4];
    const float* gbhh = (const float*)d_in[5];
    const float* pWih = (const float*)d_in[6];
    const float* pWhh = (const float*)d_in[7];
    const float* pbih = (const float*)d_in[8];
    const float* pbhh = (const float*)d_in[9];
    const float* eWih = (const float*)d_in[10];
    const float* eWhh = (const float*)d_in[11];
    const float* ebih = (const float*)d_in[12];
    const float* ebhh = (const float*)d_in[13];
    float* out = (float*)d_out;

    // Workspace layout (~140 MB total):
    char* ws = (char*)d_ws;
    size_t off = 0;
    auto alloc = [&](size_t nfloats) {
        float* p = (float*)(ws + off);
        off += nfloats * sizeof(float);
        return p;
    };
    float* A4g = alloc((size_t)UU * UU * 4); float* B2g = alloc((size_t)UU * UU * 2);
    float* A4p = alloc((size_t)UU * UU * 4); float* B2p = alloc((size_t)UU * UU * 2);
    float* A4e = alloc((size_t)UU * UU * 4); float* B2e = alloc((size_t)UU * UU * 2);
    float* hist = alloc((size_t)(TT + 1) * BB * UU);  // hist[i] = g_{i-1}, hist[0] = 0
    float* qall = alloc((size_t)TT * BB * UU);
    float* pbuf = alloc((size_t)2 * BB * UU);         // p0 / p1
    float* pnew = alloc((size_t)BB * UU);
    float* ct   = alloc((size_t)BB * UU);

    transpack_kernel<<<1024, 256, 0, stream>>>(gWih, gWhh, A4g, B2g);
    transpack_kernel<<<1024, 256, 0, stream>>>(pWih, pWhh, A4p, B2p);
    transpack_kernel<<<1024, 256, 0, stream>>>(eWih, eWhh, A4e, B2e);
    qall_kernel<<<dim3(256, 32), 256, 0, stream>>>(inputs, gW, qall);
    init_kernel<<<128, 256, 0, stream>>>(hist, pbuf);

    for (int t = 0; t < TT; ++t) {
        int par = t & 1;
        float* pb = pbuf + (size_t)par * BB * UU;
        k1_kernel<<<160, 256, 0, stream>>>(inputs, t, pb,
                                           hist + (size_t)t * BB * UU,
                                           hist + (size_t)(t + 1) * BB * UU,
                                           A4g, B2g, gbih, gbhh,
                                           hist, qall, ct);
        k2_kernel<<<128, 256, 0, stream>>>(inputs, t, ct, pb,
                                           A4p, B2p, pbih, pbhh, pnew);
        k3_kernel<<<128, 256, 0, stream>>>(pnew,
                                           t ? out + (size_t)(t - 1) * UU : nullptr,
                                           A4e, B2e, ebih, ebhh,
                                           out + (size_t)t * UU, pb);
    }
}

// Round 2
// 16263.451 us; speedup vs baseline: 8.7512x; 8.7512x over previous
//
#include <hip/hip_runtime.h>
#include <math.h>

// Problem constants: U=H=1024, B=32, T=256.
#define UU 1024
#define BB 32
#define TT 256
#define KC2 64   // k-chunk staged in LDS
#define JB 8     // j columns per GEMM block

// ---------------------------------------------------------------------------
// Weight transpose+pack: W_ih/W_hh (3U x U) row-major ->
//   A4[k][j][4] = {ih_r, ih_z, ih_n, hh_r}, B2[k][j][2] = {hh_z, hh_n}
// ---------------------------------------------------------------------------
__global__ void transpack_kernel(const float* __restrict__ Wih,
                                 const float* __restrict__ Whh,
                                 float* __restrict__ A4,
                                 float* __restrict__ B2) {
    __shared__ float s[6][32][33];
    int bk = blockIdx.x & 31;
    int bj = blockIdx.x >> 5;
    int k0 = bk * 32, j0 = bj * 32;
    int tid = threadIdx.x;
    int kc = tid & 31, jr = tid >> 5;
    for (int g = 0; g < 6; ++g) {
        const float* src = (g < 3 ? Wih : Whh) + ((size_t)((g % 3) * UU + j0)) * UU + k0;
        for (int j2 = jr; j2 < 32; j2 += 8)
            s[g][kc][j2] = src[(size_t)j2 * UU + kc];
    }
    __syncthreads();
    for (int it = 0; it < 16; ++it) {
        int e = it * 256 + tid;
        int kk = e >> 7, rem = e & 127, jj = rem >> 2, c = rem & 3;
        A4[((size_t)(k0 + kk) * UU + j0 + jj) * 4 + c] = s[c][kk][jj];
    }
    for (int it = 0; it < 8; ++it) {
        int e = it * 256 + tid;
        int kk = e >> 6, rem = e & 63, jj = rem >> 1, c = rem & 1;
        B2[((size_t)(k0 + kk) * UU + j0 + jj) * 2 + c] = s[4 + c][kk][jj];
    }
}

// ---------------------------------------------------------------------------
// q_all[t][b][u] = sum_k inputs[b][t][k] * global_W[k][u]
// ---------------------------------------------------------------------------
__global__ void qall_kernel(const float* __restrict__ x,
                            const float* __restrict__ gW,
                            float* __restrict__ q) {
    __shared__ float xs[32][KC2 + 1];
    int r0 = blockIdx.x * 32, u0 = blockIdx.y * 32;
    int tid = threadIdx.x;
    int rr = tid >> 3, ju = tid & 7;
    float4 acc = {0.f, 0.f, 0.f, 0.f};
    for (int k0 = 0; k0 < UU; k0 += KC2) {
        for (int e = tid; e < 32 * KC2; e += 256) {
            int lr = e >> 6, lk = e & 63;
            int r = r0 + lr;
            int tt = r >> 5, bb = r & 31;
            xs[lr][lk] = x[((size_t)bb * TT + tt) * UU + k0 + lk];
        }
        __syncthreads();
        #pragma unroll 4
        for (int kk = 0; kk < KC2; ++kk) {
            float4 gv = *(const float4*)&gW[(size_t)(k0 + kk) * UU + u0 + ju * 4];
            float xv = xs[rr][kk];
            acc.x += xv * gv.x; acc.y += xv * gv.y;
            acc.z += xv * gv.z; acc.w += xv * gv.w;
        }
        __syncthreads();
    }
    *(float4*)&q[(size_t)(r0 + rr) * UU + u0 + ju * 4] = acc;
}

// Zero hist row 0, P slots (par,pp=0); prep xg slots for t=0,1 (p_cur = 0).
__global__ void init_kernel(const float* __restrict__ inputs,
                            float* __restrict__ hist,
                            float* __restrict__ P,
                            float* __restrict__ xg) {
    int i = blockIdx.x * 256 + threadIdx.x;  // 0..32767
    int b = i >> 10, u = i & 1023;
    hist[i] = 0.f;
    P[i] = 0.f;                       // slot 0 = par0,pp0
    P[(size_t)2 * BB * UU + i] = 0.f; // slot 2 = par1,pp0
    xg[i] = inputs[(size_t)b * TT * UU + u];                 // u_0
    xg[(size_t)BB * UU + i] = inputs[(size_t)b * TT * UU + UU + u];  // u_1
}

// ---------------------------------------------------------------------------
// Shared-memory unions for the fused stage kernel
// ---------------------------------------------------------------------------
struct GruSmem {
    float4 a4s[KC2][JB];
    float2 b2s[KC2][JB];
    float xs[BB][KC2 + 4];
    float hs[BB][KC2 + 4];
};
struct AttSmem {
    float sc[TT];
    float red[8];
    float pct[4][UU];
};
union StageSmem { GruSmem g; AttSmem a; };

// ---------------------------------------------------------------------------
// Fused GRU cell: 8 j-columns x 32 batches per block, K=1024 via LDS chunks.
// x: [B][U] stride UU (pre-prepped). hIn: stride sh (nullptr -> zeros).
// Optional epilogue: epiDst[b*UU+j] = epiU[b*sEpiU + j] + h_new  (xg prep).
// ---------------------------------------------------------------------------
__device__ __forceinline__ void gru_cell(
    GruSmem* sm, int jblk, int tid,
    const float* __restrict__ x,
    const float* __restrict__ hIn, size_t sh,
    const float* __restrict__ A4, const float* __restrict__ B2,
    const float* __restrict__ bih, const float* __restrict__ bhh,
    float* __restrict__ hOut, size_t sout,
    const float* __restrict__ epiU, size_t sEpiU, float* __restrict__ epiDst) {
    int b = tid >> 3, jj = tid & 7;
    int j0 = jblk * JB;
    int j = j0 + jj;
    float air = 0.f, aiz = 0.f, ain = 0.f, ahr = 0.f, ahz = 0.f, ahn = 0.f;
    for (int k0 = 0; k0 < UU; k0 += KC2) {
        // stage weights: 512 float4 + 512 float2
        int e = tid;
        #pragma unroll
        for (int it = 0; it < 2; ++it, e += 256) {
            int kk = e >> 3, jw = e & 7;
            sm->a4s[kk][jw] = *(const float4*)&A4[((size_t)(k0 + kk) * UU + j0 + jw) * 4];
            sm->b2s[kk][jw] = *(const float2*)&B2[((size_t)(k0 + kk) * UU + j0 + jw) * 2];
        }
        // stage x/h: 32 rows x 16 float4 each
        e = tid;
        #pragma unroll
        for (int it = 0; it < 2; ++it, e += 256) {
            int lb = e >> 4, lk = e & 15;
            *(float4*)&sm->xs[lb][lk * 4] = *(const float4*)&x[(size_t)lb * UU + k0 + lk * 4];
            float4 hv = {0.f, 0.f, 0.f, 0.f};
            if (hIn) hv = *(const float4*)&hIn[(size_t)lb * sh + k0 + lk * 4];
            *(float4*)&sm->hs[lb][lk * 4] = hv;
        }
        __syncthreads();
        #pragma unroll 8
        for (int kk = 0; kk < KC2; ++kk) {
            float4 wa = sm->a4s[kk][jj];
            float2 wb = sm->b2s[kk][jj];
            float xv = sm->xs[b][kk], hv = sm->hs[b][kk];
            air += xv * wa.x; aiz += xv * wa.y; ain += xv * wa.z;
            ahr += hv * wa.w; ahz += hv * wb.x; ahn += hv * wb.y;
        }
        __syncthreads();
    }
    float hprev = hIn ? hIn[(size_t)b * sh + j] : 0.f;
    float r = 1.f / (1.f + expf(-(air + bih[j] + ahr + bhh[j])));
    float z = 1.f / (1.f + expf(-(aiz + bih[UU + j] + ahz + bhh[UU + j])));
    float n = tanhf(ain + bih[2 * UU + j] + r * (ahn + bhh[2 * UU + j]));
    float val = (1.f - z) * n + z * hprev;
    hOut[(size_t)b * sout + j] = val;
    if (epiDst) epiDst[(size_t)b * UU + j] = epiU[(size_t)b * sEpiU + j] + val;
}

// ---------------------------------------------------------------------------
// Attention for one batch b: scores over hist[0..t], softmax, context.
// Writes xp[b][u] = u_t[b][u] + ct[b][u].
// ---------------------------------------------------------------------------
__device__ __forceinline__ void attention_body(
    AttSmem* sm, int b, int tid, int t,
    const float* __restrict__ hist,
    const float* __restrict__ q,    // qall + t*B*U
    const float* __restrict__ ut,   // inputs + t*U (stride T*U per b)
    float* __restrict__ xp) {
    int nt = t + 1;
    int wave = tid >> 6, lane = tid & 63;
    const float* qb = q + (size_t)b * UU;
    float4 qr[4];
    #pragma unroll
    for (int m = 0; m < 4; ++m) qr[m] = *(const float4*)&qb[m * 256 + lane * 4];
    for (int tp = wave; tp < nt; tp += 4) {
        const float* hr = hist + ((size_t)tp * BB + b) * UU;
        float s = 0.f;
        #pragma unroll
        for (int m = 0; m < 4; ++m) {
            float4 hv = *(const float4*)&hr[m * 256 + lane * 4];
            s += hv.x * qr[m].x + hv.y * qr[m].y + hv.z * qr[m].z + hv.w * qr[m].w;
        }
        #pragma unroll
        for (int off = 32; off; off >>= 1) s += __shfl_xor(s, off);
        if (lane == 0) sm->sc[tp] = s;
    }
    __syncthreads();
    float v = (tid < nt) ? sm->sc[tid] : -INFINITY;
    float mx = v;
    #pragma unroll
    for (int off = 32; off; off >>= 1) mx = fmaxf(mx, __shfl_xor(mx, off));
    if (lane == 0) sm->red[wave] = mx;
    __syncthreads();
    mx = fmaxf(fmaxf(sm->red[0], sm->red[1]), fmaxf(sm->red[2], sm->red[3]));
    float ev = (tid < nt) ? expf(v - mx) : 0.f;
    float sum = ev;
    #pragma unroll
    for (int off = 32; off; off >>= 1) sum += __shfl_xor(sum, off);
    if (lane == 0) sm->red[4 + wave] = sum;
    __syncthreads();
    float inv = 1.f / (sm->red[4] + sm->red[5] + sm->red[6] + sm->red[7]);
    if (tid < nt) sm->sc[tid] = ev * inv;
    __syncthreads();
    // context: per-wave partials in registers over tp = wave, wave+4, ...
    float4 acc[4];
    #pragma unroll
    for (int m = 0; m < 4; ++m) acc[m] = {0.f, 0.f, 0.f, 0.f};
    for (int tp = wave; tp < nt; tp += 4) {
        float a = sm->sc[tp];
        const float* hr = hist + ((size_t)tp * BB + b) * UU;
        #pragma unroll
        for (int m = 0; m < 4; ++m) {
            float4 hv = *(const float4*)&hr[m * 256 + lane * 4];
            acc[m].x += a * hv.x; acc[m].y += a * hv.y;
            acc[m].z += a * hv.z; acc[m].w += a * hv.w;
        }
    }
    #pragma unroll
    for (int m = 0; m < 4; ++m)
        *(float4*)&sm->pct[wave][m * 256 + lane * 4] = acc[m];
    __syncthreads();
    int u0 = tid * 4;
    float4 c = {0.f, 0.f, 0.f, 0.f};
    #pragma unroll
    for (int w = 0; w < 4; ++w) {
        float4 pv = *(const float4*)&sm->pct[w][u0];
        c.x += pv.x; c.y += pv.y; c.z += pv.z; c.w += pv.w;
    }
    float4 uv = *(const float4*)&ut[(size_t)b * TT * UU + u0];
    c.x += uv.x; c.y += uv.y; c.z += uv.z; c.w += uv.w;
    *(float4*)&xp[(size_t)b * UU + u0] = c;
}

// ---------------------------------------------------------------------------
// One stage S_t = { g(t), att(t), p(t-1), e(t-2) } — mutually independent.
// Blocks: [0,128) g | [128,256) p | [256,384) e | [384,416) att.
// ---------------------------------------------------------------------------
__global__ __launch_bounds__(256, 2)
void stage_kernel(int t, const float* __restrict__ inputs,
                  float* __restrict__ hist, float* __restrict__ P,
                  float* __restrict__ xg, float* __restrict__ xp,
                  const float* __restrict__ qall, float* __restrict__ out,
                  const float* __restrict__ A4g, const float* __restrict__ B2g,
                  const float* __restrict__ gbih, const float* __restrict__ gbhh,
                  const float* __restrict__ A4p, const float* __restrict__ B2p,
                  const float* __restrict__ pbih, const float* __restrict__ pbhh,
                  const float* __restrict__ A4e, const float* __restrict__ B2e,
                  const float* __restrict__ ebih, const float* __restrict__ ebhh) {
    __shared__ StageSmem sm;
    int blk = blockIdx.x;
    int tid = threadIdx.x;
    if (blk < 128) {
        if (t < TT)
            gru_cell(&sm.g, blk, tid,
                     xg + (size_t)(t & 1) * BB * UU,
                     hist + (size_t)t * BB * UU, UU,
                     A4g, B2g, gbih, gbhh,
                     hist + (size_t)(t + 1) * BB * UU, UU,
                     nullptr, 0, nullptr);
    } else if (blk < 256) {
        int tp = t - 1;
        if (tp >= 0 && tp < TT) {
            int par = tp & 1, pp = (tp >> 1) & 1;
            const float* hP = P + (size_t)(par * 2 + pp) * BB * UU;
            float* oP = P + (size_t)(par * 2 + (1 - pp)) * BB * UU;
            const float* epiU = (tp + 2 < TT) ? inputs + (size_t)(tp + 2) * UU : nullptr;
            float* epiDst = epiU ? xg + (size_t)(tp & 1) * BB * UU : nullptr;
            gru_cell(&sm.g, blk - 128, tid,
                     xp + (size_t)(tp & 1) * BB * UU,
                     hP, UU,
                     A4p, B2p, pbih, pbhh,
                     oP, UU,
                     epiU, (size_t)TT * UU, epiDst);
        }
    } else if (blk < 384) {
        int te = t - 2;
        if (te >= 0 && te < TT) {
            int par = te & 1, pp = (te >> 1) & 1;
            const float* xE = P + (size_t)(par * 2 + (1 - pp)) * BB * UU;  // p(te)
            const float* hE = te ? out + (size_t)(te - 1) * UU : nullptr;
            gru_cell(&sm.g, blk - 256, tid,
                     xE, hE, (size_t)TT * UU,
                     A4e, B2e, ebih, ebhh,
                     out + (size_t)te * UU, (size_t)TT * UU,
                     nullptr, 0, nullptr);
        }
    } else {
        if (t < TT)
            attention_body(&sm.a, blk - 384, tid, t, hist,
                           qall + (size_t)t * BB * UU,
                           inputs + (size_t)t * UU,
                           xp + (size_t)(t & 1) * BB * UU);
    }
}

extern "C" void kernel_launch(void* const* d_in, const int* in_sizes, int n_in,
                              void* d_out, int out_size, void* d_ws, size_t ws_size,
                              hipStream_t stream) {
    (void)in_sizes; (void)n_in; (void)out_size; (void)ws_size;
    const float* inputs = (const float*)d_in[0];
    const float* gW   = (const float*)d_in[1];
    const float* gWih = (const float*)d_in[2];
    const float* gWhh = (const float*)d_in[3];
    const float* gbih = (const float*)d_in[4];
    const float* gbhh = (const float*)d_in[5];
    const float* pWih = (const float*)d_in[6];
    const float* pWhh = (const float*)d_in[7];
    const float* pbih = (const float*)d_in[8];
    const float* pbhh = (const float*)d_in[9];
    const float* eWih = (const float*)d_in[10];
    const float* eWhh = (const float*)d_in[11];
    const float* ebih = (const float*)d_in[12];
    const float* ebhh = (const float*)d_in[13];
    float* out = (float*)d_out;

    char* ws = (char*)d_ws;
    size_t off = 0;
    auto alloc = [&](size_t nfloats) {
        float* p = (float*)(ws + off);
        off += nfloats * sizeof(float);
        return p;
    };
    float* A4g = alloc((size_t)UU * UU * 4); float* B2g = alloc((size_t)UU * UU * 2);
    float* A4p = alloc((size_t)UU * UU * 4); float* B2p = alloc((size_t)UU * UU * 2);
    float* A4e = alloc((size_t)UU * UU * 4); float* B2e = alloc((size_t)UU * UU * 2);
    float* hist = alloc((size_t)(TT + 1) * BB * UU);
    float* qall = alloc((size_t)TT * BB * UU);
    float* P    = alloc((size_t)4 * BB * UU);   // [par][pp]
    float* xg   = alloc((size_t)2 * BB * UU);   // g-cell x, slot t&1
    float* xp   = alloc((size_t)2 * BB * UU);   // p-cell x, slot t&1

    transpack_kernel<<<1024, 256, 0, stream>>>(gWih, gWhh, A4g, B2g);
    transpack_kernel<<<1024, 256, 0, stream>>>(pWih, pWhh, A4p, B2p);
    transpack_kernel<<<1024, 256, 0, stream>>>(eWih, eWhh, A4e, B2e);
    qall_kernel<<<dim3(256, 32), 256, 0, stream>>>(inputs, gW, qall);
    init_kernel<<<128, 256, 0, stream>>>(inputs, hist, P, xg);

    for (int t = 0; t <= TT + 1; ++t) {
        stage_kernel<<<416, 256, 0, stream>>>(t, inputs, hist, P, xg, xp, qall, out,
                                              A4g, B2g, gbih, gbhh,
                                              A4p, B2p, pbih, pbhh,
                                              A4e, B2e, ebih, ebhh);
    }
}